// Round 1
// baseline (702.981 us; speedup 1.0000x reference)
//
#include <hip/hip_runtime.h>

// Linear-attention decode step.
// out[b,h,e] = valid(b) ? (q·k)[b,h]*v[b,h,e] + exp(-slope[h]) * sum_d q[b,h,d]*KV[slot[b],h,d,e] : 0
// Shapes: q/k/v (B,H,1,D) f32, kv_caches (S,H,D,D) f32, slope (H,) f32, slot (B,) i32.
// B=128 H=64 D=96 S=256. Memory-bound on the gathered (B,H,D,D) cache read (~302 MB).

#define NB 128
#define NH 64
#define ND 96
#define NS 256

__global__ __launch_bounds__(128, 4) void la_decode(
    const float* __restrict__ q, const float* __restrict__ k,
    const float* __restrict__ v, const float* __restrict__ kvc,
    const float* __restrict__ slope, const int* __restrict__ slot_idx,
    float* __restrict__ out)
{
    const int bid = blockIdx.x;
    const int h = bid >> 7;        // h-major: blocks sharing a slot (same b) are close in dispatch
    const int b = bid & (NB - 1);
    const int t = threadIdx.x;

    __shared__ float qs[ND];
    __shared__ float red[128];

    const int slot = slot_idx[b];
    const bool valid = slot >= 0;
    const int safe = valid ? slot : 0;

    const int bh = b * NH + h;

    // Stage q into LDS and form q·k partial products.
    float p = 0.f;
    if (t < ND) {
        float qv = q[bh * ND + t];
        qs[t] = qv;
        p = qv * k[bh * ND + t];
    }
    red[t] = p;
    __syncthreads();

    // Tree-reduce 128 partials -> red[0] (threads 96..127 contributed 0).
    #pragma unroll
    for (int s = 64; s > 0; s >>= 1) {
        if (t < s) red[t] += red[t + s];
        __syncthreads();
    }
    const float qk = red[0];

    if (t < ND) {
        // Mat-vec: acc[e] = sum_d q[d] * KV[safe, h, d, e]; e = t, stride ND along d.
        const float* __restrict__ kp =
            kvc + ((size_t)safe * NH + h) * (size_t)(ND * ND) + t;
        float acc = 0.f;
        #pragma unroll 16
        for (int d = 0; d < ND; ++d)
            acc = fmaf(qs[d], kp[(size_t)d * ND], acc);

        const float ratio = expf(-slope[h]);
        const float o = valid ? fmaf(qk, v[bh * ND + t], ratio * acc) : 0.f;
        out[bh * ND + t] = o;
    }
}

extern "C" void kernel_launch(void* const* d_in, const int* in_sizes, int n_in,
                              void* d_out, int out_size, void* d_ws, size_t ws_size,
                              hipStream_t stream) {
    const float* q     = (const float*)d_in[0];
    const float* k     = (const float*)d_in[1];
    const float* v     = (const float*)d_in[2];
    const float* kvc   = (const float*)d_in[3];
    const float* slope = (const float*)d_in[4];
    const int*   slot  = (const int*)d_in[5];
    float* out = (float*)d_out;

    dim3 grid(NB * NH);   // one block per (b,h), h-major
    dim3 block(128);
    la_decode<<<grid, block, 0, stream>>>(q, k, v, kvc, slope, slot, out);
}

// Round 2
// 701.333 us; speedup vs baseline: 1.0023x; 1.0023x over previous
//
#include <hip/hip_runtime.h>

// Linear-attention decode step.
// out[b,h,e] = valid(b) ? (q·k)[b,h]*v[b,h,e] + exp(-slope[h]) * sum_d q[b,h,d]*KV[slot[b],h,d,e] : 0
// Shapes: q/k/v (B,H,1,D) f32, kv_caches (S,H,D,D) f32, slope (H,) f32, slot (B,) i32.
// B=128 H=64 D=96 S=256. Memory-bound: gathered cache read = B*H*D*D*4 = 302 MB -> ~48 us floor.
//
// R1: float4-contiguous tile read. Lane map t<96: dp=t/24 (d-partition), e4=t%24
// (float4 column group). Per iteration j (d = j*4+dp), lane address is
// base + j*1536 + 16*t  -> byte-contiguous 16B/lane stream, 4x fewer VMEM insts.

#define NB 128
#define NH 64
#define ND 96
#define NS 256

__global__ __launch_bounds__(128, 4) void la_decode(
    const float* __restrict__ q, const float* __restrict__ k,
    const float* __restrict__ v, const float* __restrict__ kvc,
    const float* __restrict__ slope, const int* __restrict__ slot_idx,
    float* __restrict__ out)
{
    const int bid = blockIdx.x;
    const int h = bid >> 7;        // h-major: duplicate-slot blocks are dispatch-adjacent
    const int b = bid & (NB - 1);
    const int t = threadIdx.x;

    __shared__ float qs[ND];
    __shared__ float red[128];
    __shared__ float part[4][ND];  // dp-partition partial sums

    const int slot = slot_idx[b];
    const bool valid = slot >= 0;
    const int safe = valid ? slot : 0;

    const int bh = b * NH + h;

    // Stage q into LDS and form q·k partial products.
    float p = 0.f;
    if (t < ND) {
        float qv = q[bh * ND + t];
        qs[t] = qv;
        p = qv * k[bh * ND + t];
    }
    red[t] = p;
    __syncthreads();

    // Tree-reduce 128 partials -> red[0].
    #pragma unroll
    for (int s = 64; s > 0; s >>= 1) {
        if (t < s) red[t] += red[t + s];
        __syncthreads();
    }
    const float qk = red[0];

    // Mat-vec over the gathered (D,D) tile, float4-contiguous.
    float4 acc = make_float4(0.f, 0.f, 0.f, 0.f);
    if (t < 96) {
        const int dp = t / 24;     // 0..3
        const int e4 = t % 24;     // 0..23
        const float* __restrict__ kp =
            kvc + ((size_t)safe * NH + h) * (size_t)(ND * ND);
        // addr(j) = kp + (j*4+dp)*ND + e4*4 = kp + j*384 + 4*t  (floats)
        const float4* __restrict__ kp4 = (const float4*)(kp + 4 * t);
        #pragma unroll 8
        for (int j = 0; j < 24; ++j) {
            const float4 kv4 = kp4[j * 96];        // 96 float4 = 384 floats per j
            const float qd = qs[j * 4 + dp];
            acc.x = fmaf(qd, kv4.x, acc.x);
            acc.y = fmaf(qd, kv4.y, acc.y);
            acc.z = fmaf(qd, kv4.z, acc.z);
            acc.w = fmaf(qd, kv4.w, acc.w);
        }
        // Stash partials: part[dp][e4*4 .. e4*4+3]
        *(float4*)&part[dp][e4 * 4] = acc;
    }
    __syncthreads();

    if (t < ND) {
        const float dot = part[0][t] + part[1][t] + part[2][t] + part[3][t];
        const float ratio = __expf(-slope[h]);
        const float o = valid ? fmaf(qk, v[bh * ND + t], ratio * dot) : 0.f;
        out[bh * ND + t] = o;
    }
}

extern "C" void kernel_launch(void* const* d_in, const int* in_sizes, int n_in,
                              void* d_out, int out_size, void* d_ws, size_t ws_size,
                              hipStream_t stream) {
    const float* q     = (const float*)d_in[0];
    const float* k     = (const float*)d_in[1];
    const float* v     = (const float*)d_in[2];
    const float* kvc   = (const float*)d_in[3];
    const float* slope = (const float*)d_in[4];
    const int*   slot  = (const int*)d_in[5];
    float* out = (float*)d_out;

    dim3 grid(NB * NH);   // one block per (b,h), h-major
    dim3 block(128);
    la_decode<<<grid, block, 0, stream>>>(q, k, v, kvc, slope, slot, out);
}